// Round 17
// baseline (1079.192 us; speedup 1.0000x reference)
//
#include <hip/hip_runtime.h>
#include <math.h>

// ---------------------------------------------------------------------------
// SpatioTemporalOutageModel:
//   GCN(14->64) -> GCN(64->64)+county_bias -> LSTM(64->128, T=336) -> MLP(128->64->1)
//
// R17 = R16 (best: 1078us) + LSTM t-loop manually unrolled x2:
//  - The allocator refuses 96-reg live ranges across the LOOP-CARRIED barrier
//    (9 schemes, R6-R14, all ~223us). Unrolling 2 steps into one body makes
//    the two steps' weight loads the SAME SSA values -> CSE merges them; the
//    allocator only needs to span ONE intra-body barrier (it already spans
//    barriers with xa/xb). Worst case it reloads per body = half the per-step
//    reload tax. tc always even; buf static 0/1 per half; halves are
//    byte-identical to the R16 body -> strictly no-worse.
//  - GCN side unchanged from R16 (f16x2 agg2, fused gcn1, folded W2, gbias).
// ---------------------------------------------------------------------------

#define T_DIM 336
#define N_DIM 3233
#define E_DIM 20000
#define FEAT  14
#define D_DIM 64
#define H_DIM 128
#define ET    (E_DIM + N_DIM)     // edges + self loops = 23233

typedef _Float16 f16;
typedef _Float16 half8_t __attribute__((ext_vector_type(8)));
typedef _Float16 half2_t __attribute__((ext_vector_type(2)));
typedef float float4_t __attribute__((ext_vector_type(4)));

__device__ __forceinline__ float sigf(float x) {
    return __builtin_amdgcn_rcpf(1.f + exp2f(-1.4426950408889634f * x));
}
__device__ __forceinline__ float tanhfast(float x) {
    return 1.f - 2.f * __builtin_amdgcn_rcpf(1.f + exp2f(2.8853900817779268f * x));
}

// ---------------- CSR build (deterministic) ----------------

__global__ void k_init(int* cnt, int* fill) {
    int i = blockIdx.x * 256 + threadIdx.x;
    if (i < N_DIM) { cnt[i] = 0; fill[i] = 0; }
}

__global__ void k_cnt(const int* __restrict__ ei, int* cnt) {
    int e = blockIdx.x * 256 + threadIdx.x;
    if (e < E_DIM) atomicAdd(&cnt[ei[E_DIM + e]], 1);
}

__global__ void k_scan(const int* __restrict__ cnt, int* __restrict__ rowp) {
    __shared__ int csum[1024];
    int tid = threadIdx.x;
    int base = tid * 4;
    int v[4];
    int s = 0;
    #pragma unroll
    for (int m = 0; m < 4; m++) {
        int idx = base + m;
        int len = (idx < N_DIM) ? (cnt[idx] + 1) : 0;
        v[m] = s; s += len;
    }
    csum[tid] = s;
    __syncthreads();
    for (int off = 1; off < 1024; off <<= 1) {
        int t2 = (tid >= off) ? csum[tid - off] : 0;
        __syncthreads();
        csum[tid] += t2;
        __syncthreads();
    }
    int pre = (tid > 0) ? csum[tid - 1] : 0;
    #pragma unroll
    for (int m = 0; m < 4; m++) {
        int idx = base + m;
        if (idx <= N_DIM) rowp[idx] = pre + v[m];
    }
}

__global__ void k_fill(const int* __restrict__ ei, const int* __restrict__ rowp,
                       int* fill, int* __restrict__ eid) {
    int e = blockIdx.x * 256 + threadIdx.x;
    if (e < ET) {
        int d = (e < E_DIM) ? ei[E_DIM + e] : (e - E_DIM);
        int p = rowp[d] + atomicAdd(&fill[d], 1);
        eid[p] = e;
    }
}

__global__ void k_sortdeg(const float* __restrict__ ew, const int* __restrict__ rowp,
                          int* __restrict__ eid, float* __restrict__ dis) {
    int n = blockIdx.x * 256 + threadIdx.x;
    if (n >= N_DIM) return;
    int p0 = rowp[n], p1 = rowp[n + 1];
    for (int i = p0 + 1; i < p1; i++) {
        int key = eid[i];
        int j = i - 1;
        while (j >= p0 && eid[j] > key) { eid[j + 1] = eid[j]; j--; }
        eid[j + 1] = key;
    }
    float deg = 0.f;
    for (int p = p0; p < p1; p++) {
        int e = eid[p];
        deg += (e < E_DIM) ? ew[e] : 1.0f;
    }
    dis[n] = rsqrtf(deg);
}

__global__ void k_csrmat(const int* __restrict__ ei, const float* __restrict__ ew,
                         const float* __restrict__ dis, const int* __restrict__ rowp,
                         const int* __restrict__ eid, int* __restrict__ csrc,
                         float* __restrict__ cnrm) {
    int n = blockIdx.x * 256 + threadIdx.x;
    if (n >= N_DIM) return;
    float dn = dis[n];
    int p0 = rowp[n], p1 = rowp[n + 1];
    for (int p = p0; p < p1; p++) {
        int e = eid[p];
        int s; float w;
        if (e < E_DIM) { s = ei[e]; w = ew[e]; }
        else           { s = e - E_DIM; w = 1.0f; }
        csrc[p] = s;
        cnrm[p] = dis[s] * w * dn;
    }
}

// ---------------- weight prep: fold W2 into Wih, pack B-fragments ----------------
__global__ void k_wprep(const float* __restrict__ W2, const float* __restrict__ Wih,
                        const float* __restrict__ Whh, f16* __restrict__ wfbuf) {
    int idx = blockIdx.x * 256 + threadIdx.x;
    if (idx >= 8 * 4 * 6 * 64) return;
    int lane = idx & 63;
    int ks = (idx >> 6) % 6;
    int ct = ((idx >> 6) / 6) & 3;
    int wv = (idx >> 6) / 24;
    int q = lane >> 4, r = lane & 15;
    int g = 128 * ct + 16 * wv + r;
    f16* dst = wfbuf + (long)idx * 8;
    if (ks < 2) {
        const float* wir = Wih + (long)g * 64;
        #pragma unroll
        for (int j = 0; j < 8; j++) {
            int k = 32 * ks + 8 * q + j;
            const float* w2r = W2 + (long)k * 64;
            float s = 0.f;
            #pragma unroll 16
            for (int d = 0; d < 64; d++) s += w2r[d] * wir[d];
            dst[j] = (f16)s;
        }
    } else {
        const float* src = Whh + (long)g * 128 + 32 * (ks - 2) + 8 * q;
        #pragma unroll
        for (int j = 0; j < 8; j++) dst[j] = (f16)src[j];
    }
}

// gbias[n][g] = bih[g]+bhh[g] + sum_d (b2[d]+county[n][d])*Wih[g][d]
__global__ void k_gbias(const float* __restrict__ county, const float* __restrict__ b2,
                        const float* __restrict__ Wih, const float* __restrict__ bih,
                        const float* __restrict__ bhh, float* __restrict__ gbias) {
    long id = (long)blockIdx.x * 256 + threadIdx.x;
    if (id >= (long)N_DIM * 512) return;
    int n = (int)(id >> 9), g = (int)(id & 511);
    const float* wir = Wih + (long)g * 64;
    const float* cn = county + (long)n * 64;
    float s = bih[g] + bhh[g];
    #pragma unroll 16
    for (int d = 0; d < 64; d++) s += (b2[d] + cn[d]) * wir[d];
    gbias[id] = s;
}

// ---------------- GCN1 fused: h = relu((A.x)@W1 + b1) -> f16 ----------------
__global__ void k_gcn1(const float* __restrict__ x, const int* __restrict__ rowp,
                       const int* __restrict__ csrc, const float* __restrict__ cnrm,
                       const float* __restrict__ W1, const float* __restrict__ b1,
                       f16* __restrict__ h, int tc) {
    __shared__ float g1[4][4][16];   // [wave][tslot][dim]
    int lane = threadIdx.x & 63;
    int wv = threadIdx.x >> 6;
    long wid = ((long)blockIdx.x * 256 + threadIdx.x) >> 6;
    int ntg = (tc + 3) >> 2;
    bool wlive = wid < (long)N_DIM * ntg;

    int n = 0, tg = 0;
    if (wlive) { n = (int)(wid % N_DIM); tg = (int)(wid / N_DIM); }
    int j = lane >> 4, d = lane & 15;
    int tj = 4 * tg + j;
    bool live = wlive && (d < FEAT) && (tj < tc);

    float acc = 0.f;
    if (wlive) {
        int p0 = rowp[n], p1 = rowp[n + 1];
        for (int p = p0; p < p1; p++) {
            int s = csrc[p];
            float w = cnrm[p];
            if (live) acc += w * x[((long)tj * N_DIM + s) * FEAT + d];
        }
    }
    g1[wv][j][d] = acc;
    __syncthreads();

    if (!wlive) return;
    float wc[FEAT];
    #pragma unroll
    for (int k = 0; k < FEAT; k++) wc[k] = W1[k * 64 + lane];
    float bb = b1[lane];
    #pragma unroll
    for (int jj = 0; jj < 4; jj++) {
        int tjj = 4 * tg + jj;
        if (tjj >= tc) break;
        float a = bb;
        #pragma unroll
        for (int k = 0; k < FEAT; k++) a += g1[wv][jj][k] * wc[k];
        h[((long)tjj * N_DIM + n) * 64 + lane] = (f16)fmaxf(a, 0.f);
    }
}

// ---------------- GCN2a: ah = A.h  (f16x2 gather, 4 timesteps/wave) ----------------
__global__ void k_agg2(const f16* __restrict__ h, const int* __restrict__ rowp,
                       const int* __restrict__ csrc, const float* __restrict__ cnrm,
                       f16* __restrict__ ah, int tc) {
    int lane = threadIdx.x & 63;
    long wid = ((long)blockIdx.x * 256 + threadIdx.x) >> 6;
    int ntg = (tc + 3) >> 2;
    if (wid >= (long)N_DIM * ntg) return;
    int n = (int)(wid % N_DIM);
    int tg = (int)(wid / N_DIM);
    int tb = 4 * tg;
    int half = lane >> 5, d2 = (lane & 31) << 1;
    int ta = tb + half;
    int tbp = tb + 2 + half;
    bool la = ta < tc, lb = tbp < tc;
    float a0 = 0.f, a1 = 0.f, b0 = 0.f, b1v = 0.f;
    int p0 = rowp[n], p1 = rowp[n + 1];
    const long strideT2 = (long)2 * N_DIM * 64;
    for (int p = p0; p < p1; p++) {
        int s = csrc[p];
        float w = cnrm[p];
        const f16* base = h + ((long)ta * N_DIM + s) * 64 + d2;
        if (la) {
            half2_t va = *(const half2_t*)base;
            a0 += w * (float)va[0];
            a1 += w * (float)va[1];
        }
        if (lb) {
            half2_t vb = *(const half2_t*)(base + strideT2);
            b0  += w * (float)vb[0];
            b1v += w * (float)vb[1];
        }
    }
    f16* dst = ah + ((long)ta * N_DIM + n) * 64 + d2;
    if (la) { half2_t oa; oa[0] = (f16)a0; oa[1] = (f16)a1; *(half2_t*)dst = oa; }
    if (lb) { half2_t ob; ob[0] = (f16)b0; ob[1] = (f16)b1v; *(half2_t*)(dst + strideT2) = ob; }
}

// ---------------- LSTM chunk (R16 config, t-loop unrolled x2) + MLP head -----------
// Wave wv owns gate-types ct={i,f,g,o} x units [16wv,16wv+16). Thread (wv,q,r):
// nodes 4q+reg, unit u=16wv+r -> all 4 gates of (node,u) live in acc[ct][reg].

#define LSTM_HALF(BUF) { \
    half8_t a2 = *(const half8_t*)&xh[BUF][r][8 * q]; \
    half8_t a3 = *(const half8_t*)&xh[BUF][r][32 + 8 * q]; \
    half8_t a4 = *(const half8_t*)&xh[BUF][r][64 + 8 * q]; \
    half8_t a5 = *(const half8_t*)&xh[BUF][r][96 + 8 * q]; \
    float4_t acc[4]; \
    _Pragma("unroll") \
    for (int ct = 0; ct < 4; ct++) { \
        acc[ct][0] = gb[ct][0]; acc[ct][1] = gb[ct][1]; \
        acc[ct][2] = gb[ct][2]; acc[ct][3] = gb[ct][3]; \
    } \
    _Pragma("unroll") \
    for (int ct = 0; ct < 4; ct++) \
        acc[ct] = __builtin_amdgcn_mfma_f32_16x16x32_f16(xa, __builtin_bit_cast(half8_t, wfr[ct][0]), acc[ct], 0, 0, 0); \
    _Pragma("unroll") \
    for (int ct = 0; ct < 4; ct++) \
        acc[ct] = __builtin_amdgcn_mfma_f32_16x16x32_f16(xb, __builtin_bit_cast(half8_t, wfr[ct][1]), acc[ct], 0, 0, 0); \
    int tn = (t + 1 < tc) ? t + 1 : t; \
    const f16* xp = ah + ((long)tn * N_DIM + xrow) * 64; \
    xa = *(const half8_t*)(xp + 8 * q); \
    xb = *(const half8_t*)(xp + 32 + 8 * q); \
    _Pragma("unroll") \
    for (int ct = 0; ct < 4; ct++) \
        acc[ct] = __builtin_amdgcn_mfma_f32_16x16x32_f16(a2, __builtin_bit_cast(half8_t, wfr[ct][2]), acc[ct], 0, 0, 0); \
    _Pragma("unroll") \
    for (int ct = 0; ct < 4; ct++) \
        acc[ct] = __builtin_amdgcn_mfma_f32_16x16x32_f16(a3, __builtin_bit_cast(half8_t, wfr[ct][3]), acc[ct], 0, 0, 0); \
    _Pragma("unroll") \
    for (int ct = 0; ct < 4; ct++) \
        acc[ct] = __builtin_amdgcn_mfma_f32_16x16x32_f16(a4, __builtin_bit_cast(half8_t, wfr[ct][4]), acc[ct], 0, 0, 0); \
    _Pragma("unroll") \
    for (int ct = 0; ct < 4; ct++) \
        acc[ct] = __builtin_amdgcn_mfma_f32_16x16x32_f16(a5, __builtin_bit_cast(half8_t, wfr[ct][5]), acc[ct], 0, 0, 0); \
    _Pragma("unroll") \
    for (int reg = 0; reg < 4; reg++) { \
        float gi = acc[0][reg], gf = acc[1][reg], gg = acc[2][reg], go = acc[3][reg]; \
        float c = sigf(gf) * cv[reg] + sigf(gi) * tanhfast(gg); \
        float hh = sigf(go) * tanhfast(c); \
        cv[reg] = c; hvv[reg] = hh; \
        xh[(BUF) ^ 1][4 * q + reg][u] = (f16)hh; \
    } \
    __syncthreads(); \
    t++; \
}

__global__ __attribute__((amdgpu_flat_work_group_size(512, 512), amdgpu_waves_per_eu(2, 2)))
void k_lstm(
    const f16* __restrict__ ah, const f16* __restrict__ wfbuf,
    const float* __restrict__ gbias,
    const float* __restrict__ Wm1, const float* __restrict__ bm1,
    const float* __restrict__ Wm2, const float* __restrict__ bm2,
    float* __restrict__ Hst, float* __restrict__ Cst,
    int tc, int do_init, int do_head, float* __restrict__ out) {
    __shared__ __align__(16) f16   xh[2][16][136];   // h, double-buffered
    __shared__ __align__(16) float hd[16][132];      // head scratch
    __shared__ __align__(16) float zs[16][64];

    int tid = threadIdx.x;
    int wv = tid >> 6, lane = tid & 63, q = lane >> 4, r = lane & 15;
    int nb = blockIdx.x * 16;
    int cnt = min(16, N_DIM - nb);
    int u = 16 * wv + r;

    // weight fragments, pinned as asm outputs (R6 configuration)
    float4_t wfr[4][6];
    #pragma unroll
    for (int ct = 0; ct < 4; ct++)
        #pragma unroll
        for (int ks = 0; ks < 6; ks++)
            wfr[ct][ks] = *(const float4_t*)&wfbuf[(long)((((wv * 4 + ct) * 6 + ks) << 6) + lane) * 8];
    #pragma unroll
    for (int ct = 0; ct < 4; ct++)
        #pragma unroll
        for (int ks = 0; ks < 6; ks++)
            asm volatile("" : "+v"(wfr[ct][ks]));

    // per-node folded bias -- pinned
    float gb[4][4];
    #pragma unroll
    for (int reg = 0; reg < 4; reg++) {
        int node = 4 * q + reg;
        int gn = nb + node; if (gn >= N_DIM) gn = N_DIM - 1;
        #pragma unroll
        for (int ct = 0; ct < 4; ct++)
            gb[ct][reg] = gbias[(long)gn * 512 + 128 * ct + u];
    }
    #pragma unroll
    for (int ct = 0; ct < 4; ct++)
        #pragma unroll
        for (int reg = 0; reg < 4; reg++)
            asm volatile("" : "+v"(gb[ct][reg]));

    // state in VGPRs
    float cv[4], hvv[4];
    #pragma unroll
    for (int reg = 0; reg < 4; reg++) {
        int node = 4 * q + reg;
        bool live = (!do_init) && (node < cnt);
        hvv[reg] = live ? Hst[(long)(nb + node) * H_DIM + u] : 0.f;
        cv[reg]  = live ? Cst[(long)(nb + node) * H_DIM + u] : 0.f;
        xh[0][node][u] = (f16)hvv[reg];
    }

    int xrow = nb + r; if (xrow >= N_DIM) xrow = N_DIM - 1;
    half8_t xa = *(const half8_t*)(ah + (long)xrow * 64 + 8 * q);
    half8_t xb = *(const half8_t*)(ah + (long)xrow * 64 + 32 + 8 * q);

    __syncthreads();

    // tc is always even (84): 2 steps per body, buf statically 0 then 1.
    // Weight loads are shared SSA values across both halves (CSE), and the
    // allocator only needs to span ONE intra-body barrier.
    int t = 0;
    int tc2 = tc >> 1;
    for (int it = 0; it < tc2; it++) {
        LSTM_HALF(0)
        LSTM_HALF(1)
    }

    #pragma unroll
    for (int reg = 0; reg < 4; reg++) {
        int node = 4 * q + reg;
        if (node < cnt) {
            Hst[(long)(nb + node) * H_DIM + u] = hvv[reg];
            Cst[(long)(nb + node) * H_DIM + u] = cv[reg];
        }
    }
    if (!do_head) return;

    #pragma unroll
    for (int reg = 0; reg < 4; reg++) hd[4 * q + reg][u] = hvv[reg];
    __syncthreads();

    for (int i = tid; i < 16 * 64; i += 512) {
        int n = i >> 6, m = i & 63;
        float a = bm1[m];
        #pragma unroll 8
        for (int k = 0; k < H_DIM; k++) a += hd[n][k] * Wm1[k * 64 + m];
        zs[n][m] = fmaxf(a, 0.f);
    }
    __syncthreads();
    if (tid < cnt) {
        float a = bm2[0];
        #pragma unroll 8
        for (int m = 0; m < 64; m++) a += zs[tid][m] * Wm2[m];
        out[nb + tid] = a;
    }
}

// ---------------------------------------------------------------------------

extern "C" void kernel_launch(void* const* d_in, const int* in_sizes, int n_in,
                              void* d_out, int out_size, void* d_ws, size_t ws_size,
                              hipStream_t stream) {
    const float* x   = (const float*)d_in[0];
    const int*   ei  = (const int*)d_in[1];
    const float* ew  = (const float*)d_in[2];
    const float* W1  = (const float*)d_in[3];
    const float* b1  = (const float*)d_in[4];
    const float* W2  = (const float*)d_in[5];
    const float* b2  = (const float*)d_in[6];
    const float* cb  = (const float*)d_in[7];
    const float* Wih = (const float*)d_in[8];
    const float* Whh = (const float*)d_in[9];
    const float* bih = (const float*)d_in[10];
    const float* bhh = (const float*)d_in[11];
    const float* Wm1 = (const float*)d_in[12];
    const float* bm1 = (const float*)d_in[13];
    const float* Wm2 = (const float*)d_in[14];
    const float* bm2 = (const float*)d_in[15];
    float* out = (float*)d_out;
    (void)in_sizes; (void)n_in; (void)out_size;

    char* ws = (char*)d_ws;
    size_t off = 0;
    auto alloc = [&](size_t bytes) -> char* {
        char* p = ws + off;
        off = (off + bytes + 255) & ~(size_t)255;
        return p;
    };
    float* dis   = (float*)alloc(N_DIM * 4);
    int*   cnt   = (int*)alloc(N_DIM * 4);
    int*   fill  = (int*)alloc(N_DIM * 4);
    int*   rowp  = (int*)alloc((N_DIM + 1) * 4);
    int*   eid   = (int*)alloc(ET * 4);
    int*   csrc  = (int*)alloc(ET * 4);
    float* cnrm  = (float*)alloc(ET * 4);
    float* Hst   = (float*)alloc((size_t)N_DIM * H_DIM * 4);
    float* Cst   = (float*)alloc((size_t)N_DIM * H_DIM * 4);
    f16*   wfbuf = (f16*)alloc((size_t)8 * 4 * 6 * 64 * 8 * 2);
    float* gbias = (float*)alloc((size_t)N_DIM * 512 * 4);

    // largest Tc dividing 336 whose chunk buffers (rows*256B: h + ah f16) fit
    const int cand[] = {336, 168, 112, 84, 56, 48, 28, 16, 8, 4};
    int Tc = 4;
    for (int i = 0; i < 10; i++) {
        size_t need = off + (size_t)cand[i] * N_DIM * 256 + 4096;
        if (need <= ws_size) { Tc = cand[i]; break; }
    }
    long rows = (long)Tc * N_DIM;
    f16* hbuf  = (f16*)alloc(rows * 128);   // h f16
    f16* ahbuf = (f16*)alloc(rows * 128);   // ah f16

    // --- one-time: CSR build + weight fold/pack + per-node gate bias ---
    k_init<<<(N_DIM + 255) / 256, 256, 0, stream>>>(cnt, fill);
    k_cnt<<<(E_DIM + 255) / 256, 256, 0, stream>>>(ei, cnt);
    k_scan<<<1, 1024, 0, stream>>>(cnt, rowp);
    k_fill<<<(ET + 255) / 256, 256, 0, stream>>>(ei, rowp, fill, eid);
    k_sortdeg<<<(N_DIM + 255) / 256, 256, 0, stream>>>(ew, rowp, eid, dis);
    k_csrmat<<<(N_DIM + 255) / 256, 256, 0, stream>>>(ei, ew, dis, rowp, eid, csrc, cnrm);
    k_wprep<<<48, 256, 0, stream>>>(W2, Wih, Whh, wfbuf);
    k_gbias<<<(int)(((long)N_DIM * 512 + 255) / 256), 256, 0, stream>>>(cb, b2, Wih, bih, bhh, gbias);

    int ntg = (Tc + 3) >> 2;
    long aggWaves = (long)N_DIM * ntg;
    int aggBlocks = (int)((aggWaves + 3) / 4);
    int lblocks   = (N_DIM + 15) / 16;
    int nChunks   = T_DIM / Tc;

    for (int c = 0; c < nChunks; c++) {
        long t0 = (long)c * Tc;
        k_gcn1<<<aggBlocks, 256, 0, stream>>>(x + t0 * N_DIM * FEAT, rowp, csrc, cnrm,
                                              W1, b1, hbuf, Tc);
        k_agg2<<<aggBlocks, 256, 0, stream>>>(hbuf, rowp, csrc, cnrm, ahbuf, Tc);
        k_lstm<<<lblocks, 512, 0, stream>>>(ahbuf, wfbuf, gbias, Wm1, bm1, Wm2, bm2,
                                            Hst, Cst, Tc, c == 0 ? 1 : 0,
                                            c == nChunks - 1 ? 1 : 0, out);
    }
}